// Round 18
// baseline (114.461 us; speedup 1.0000x reference)
//
#include <hip/hip_runtime.h>
#include <hip/hip_bf16.h>
#include <stdint.h>

#define NROW 10000
#define DIM 128
#define NP 10240          // rows padded to 640 tiles of 16
#define KSEL 15
#define JC 32             // j-chunks; cells per row = JC*4 = 128
#define NTILES (NP / 16)  // 640
#define TPC (NTILES / JC) // 20

typedef __attribute__((ext_vector_type(4))) float f32x4;
typedef __attribute__((ext_vector_type(8))) short s16x8;
using bf16_t = __hip_bfloat16;

#define GLD16(gsrc, ldst)                                                          \
    __builtin_amdgcn_global_load_lds(                                              \
        (const __attribute__((address_space(1))) void*)(gsrc),                     \
        (__attribute__((address_space(3))) void*)(ldst), 16, 0, 0)

// ---------------------------------------------------------------- convert
// One wave per row. Writes X in MFMA-fragment-packed layout; sqh = 1024-0.5*|x|^2
// (MFMA C-in). Pad rows: zero data, sqh=1.0 -> key ~1.0, never beats real (~900+).
__global__ __launch_bounds__(256)
void knn_convert(const float* __restrict__ x0, const float* __restrict__ x1,
                 bf16_t* __restrict__ xp, float* __restrict__ sqh,
                 unsigned* __restrict__ counter)
{
    if (blockIdx.x == 0 && threadIdx.x == 0) *counter = 0u;
    const int rg   = blockIdx.x * 4 + (threadIdx.x >> 6);
    const int lane = threadIdx.x & 63;
    if (rg >= 2 * NP) return;
    const int m = rg >= NP ? 1 : 0;
    const int r = rg - m * NP;
    const float* src = m ? x1 : x0;

    float2 v = make_float2(0.f, 0.f);
    float  s = 0.f;
    if (r < NROW) {
        v = *(const float2*)(src + (size_t)r * DIM + lane * 2);
        s = v.x * v.x + v.y * v.y;
    }
    const uint32_t pk = (uint32_t)__bfloat16_as_ushort(__float2bfloat16(v.x))
                      | ((uint32_t)__bfloat16_as_ushort(__float2bfloat16(v.y)) << 16);
    const int e   = lane * 2;
    const int kk  = e >> 5;
    const int gg  = (e >> 3) & 3;
    const int pos = e & 7;
    const size_t off = ((((size_t)m * NTILES + (r >> 4)) * 4 + kk) * 64
                        + (size_t)(gg * 16 + (r & 15))) * 8 + pos;   // even
    *(uint32_t*)(xp + off) = pk;
    #pragma unroll
    for (int o = 32; o; o >>= 1) s += __shfl_down(s, o);
    if (lane == 0) sqh[m * NP + r] = (r < NROW) ? fmaf(s, -0.5f, 1024.0f) : 1.0f;
}

// ---------------------------------------------------------------- main
// Key = dot(Xj,Xi) + 1024 - 0.5*sq[j] (bias in MFMA C-in), truncated to 22 bits
// with 10-bit chunk-local index in the low bits. LCAP=1 cell max per
// (i, chunk, group) — 128 cells/row. QUAD B-TILES (64 i / wave, 256 i / block).
// NEW: the A-stream is LDS-STAGED — all 4 waves cooperatively global_load_lds
// the 4KB j-tile ONCE per block (vs 4x redundant per-wave global reads), double
// buffered, one barrier per tile; staging for t+1 issues right after the
// barrier so it lands under a full tile of compute. Hot-loop A-loads are
// conflict-free ds_read_b128 (~120cyc) instead of contended-L2 (~500+cyc).
#define PACKMAX(acc, idxb, Q)                                                     \
    do {                                                                          \
        const uint32_t k0_ = (__float_as_uint((acc)[0]) & 0xFFFFFC00u) | (idxb);  \
        const uint32_t k1_ = (__float_as_uint((acc)[1]) & 0xFFFFFC00u) | ((idxb) | 1u); \
        const uint32_t k2_ = (__float_as_uint((acc)[2]) & 0xFFFFFC00u) | ((idxb) | 2u); \
        const uint32_t k3_ = (__float_as_uint((acc)[3]) & 0xFFFFFC00u) | ((idxb) | 3u); \
        asm("v_max3_u32 %0, %1, %2, %0" : "+v"(Q) : "v"(k0_), "v"(k1_));          \
        asm("v_max3_u32 %0, %1, %2, %0" : "+v"(Q) : "v"(k2_), "v"(k3_));          \
    } while (0)

#define MFMA4(d, set, cin)                                                        \
    f32x4 d = __builtin_amdgcn_mfma_f32_16x16x32_bf16(a0, bfr##set[0], cin, 0, 0, 0); \
    d = __builtin_amdgcn_mfma_f32_16x16x32_bf16(a1, bfr##set[1], d, 0, 0, 0);     \
    d = __builtin_amdgcn_mfma_f32_16x16x32_bf16(a2, bfr##set[2], d, 0, 0, 0);     \
    d = __builtin_amdgcn_mfma_f32_16x16x32_bf16(a3, bfr##set[3], d, 0, 0, 0)

__global__ __launch_bounds__(256, 3)
void knn_topk(const bf16_t* __restrict__ xp, const float* __restrict__ sqh,
              uint32_t* __restrict__ pk2, uint16_t* __restrict__ px2)
{
    __shared__ bf16_t Abuf[2][2048];   // 2 x 4KB j-tile double buffer
    __shared__ float  Sbuf[512];       // chunk sq (TPC*16=320 used; padded)

    const int m     = blockIdx.z;
    const int chunk = blockIdx.y;
    const int ib    = blockIdx.x * 256;
    const int wave  = threadIdx.x >> 6;
    const int lane  = threadIdx.x & 63;
    const int li    = lane & 15;
    const int g     = lane >> 4;
    const int tid   = threadIdx.x;

    const bf16_t* XP = xp + (size_t)m * NP * DIM;
    const float*  SQ = sqh + m * NP;

    const int t0 = chunk * TPC;
    const bf16_t* XC = XP + (size_t)t0 * 2048;
    const float*  SC = SQ + t0 * 16;

    // Stage sq chunk (waves 0,1: 2KB) and A-tile 0; barrier at loop top drains.
    if (wave < 2)
        GLD16(SC + (size_t)(wave * 64 + lane) * 4, &Sbuf[wave * 256]);
    GLD16(XC + (size_t)tid * 8, &Abuf[0][wave * 512]);

    // B fragments for four i-sets (persistent; loaded via normal global loads).
    const int ti0 = (ib >> 4) + wave * 4;
    s16x8 bfr0[4], bfr1[4], bfr2[4], bfr3[4];
    #pragma unroll
    for (int kk = 0; kk < 4; ++kk) {
        const size_t bo = ((size_t)kk * 64 + (size_t)(g * 16 + li)) * 8;
        bfr0[kk] = *(const s16x8*)(XP + (size_t)ti0 * 2048 + bo);
        bfr1[kk] = *(const s16x8*)(XP + (size_t)(ti0 + 1) * 2048 + bo);
        bfr2[kk] = *(const s16x8*)(XP + (size_t)(ti0 + 2) * 2048 + bo);
        bfr3[kk] = *(const s16x8*)(XP + (size_t)(ti0 + 3) * 2048 + bo);
    }

    uint32_t q0 = 0, q1 = 0, q2 = 0, q3 = 0;   // cell max per i-set

    const bf16_t* pf = XC + 2048 + (size_t)tid * 8;   // staging src for tile t+1

    for (int t = 0; t < TPC; ++t) {
        __syncthreads();   // buf[t&1] staged (iter t-1) & prior reads of buf[(t+1)&1] done

        // A-frags + sq for tile t from LDS (conflict-free lane-contiguous b128).
        const bf16_t* ab = &Abuf[t & 1][lane * 8];
        const s16x8 a0 = *(const s16x8*)(ab);
        const s16x8 a1 = *(const s16x8*)(ab + 512);
        const s16x8 a2 = *(const s16x8*)(ab + 1024);
        const s16x8 a3 = *(const s16x8*)(ab + 1536);
        const f32x4 sv = *(const f32x4*)&Sbuf[t * 16 + g * 4];

        // Stage tile t+1 into the other buffer (lands during this tile's MFMAs;
        // overrun at t=TPC-1 reads pad, never consumed).
        GLD16(pf, &Abuf[(t + 1) & 1][wave * 512]);
        pf += 2048;

        MFMA4(acc0, 0, sv);
        MFMA4(acc1, 1, sv);
        MFMA4(acc2, 2, sv);
        MFMA4(acc3, 3, sv);

        const uint32_t ib4 = (uint32_t)(t << 2);
        PACKMAX(acc0, ib4, q0);
        PACKMAX(acc1, ib4, q1);
        PACKMAX(acc2, ib4, q2);
        PACKMAX(acc3, ib4, q3);
    }

    // Store cell max + reconstructed j. Plane = (m*JC+chunk)*4 + g, index i.
    const size_t base = ((size_t)((m * JC + chunk) * 4 + g)) * NP;
    #pragma unroll
    for (int s = 0; s < 4; ++s) {
        const uint32_t q = (s == 0) ? q0 : (s == 1) ? q1 : (s == 2) ? q2 : q3;
        const uint32_t id = q & 1023u;
        const int j = (t0 + (int)(id >> 2)) * 16 + g * 4 + (int)(id & 3u);
        const int i = ib + wave * 64 + s * 16 + li;
        pk2[base + i] = q;
        px2[base + i] = (uint16_t)j;
    }
}

// ---------------------------------------------------------------- select + count
// One thread per (row, matrix), TWO-PASS STREAMING (no register arrays -> no
// scratch spill, the round-17 pathology): pass 1 streams the 128 cell maxes
// through a med3 insert chain; pass 2 re-streams (L2-hot) and collects the ids
// >= thr (exactly 15 pass; keys unique via index bits). LDS 15x15 intersection.
#define INS(k, hi, lo) asm("v_med3_u32 %0, %1, %2, %0" : "+v"(lo) : "v"(k), "v"(hi))

__global__ __launch_bounds__(256, 1)
void knn_select_count(const uint32_t* __restrict__ pk2, const uint16_t* __restrict__ px2,
                      unsigned* __restrict__ counter)
{
    __shared__ uint16_t ids[256][KSEL + 3];   // 36B row stride -> bank-shifted
    __shared__ int wsum[4];
    const int tid  = blockIdx.x * 256 + threadIdx.x;
    const int m    = tid & 1;
    const int i    = tid >> 1;
    const int lane = threadIdx.x & 63;
    const int wave = threadIdx.x >> 6;

    if (i < NROW) {
        const uint32_t* pv = pk2 + (size_t)m * 128 * NP + i;
        const uint16_t* px = px2 + (size_t)m * 128 * NP + i;
        uint32_t q0 = 0, q1 = 0, q2 = 0, q3 = 0, q4 = 0, q5 = 0, q6 = 0, q7 = 0,
                 q8 = 0, q9 = 0, q10 = 0, q11 = 0, q12 = 0, q13 = 0, q14 = 0;
        #pragma unroll
        for (int c = 0; c < 128; ++c) {
            const uint32_t kc = pv[(size_t)c * NP];
            INS(kc, q13, q14); INS(kc, q12, q13); INS(kc, q11, q12); INS(kc, q10, q11);
            INS(kc, q9,  q10); INS(kc, q8,  q9);  INS(kc, q7,  q8);  INS(kc, q6,  q7);
            INS(kc, q5,  q6);  INS(kc, q4,  q5);  INS(kc, q3,  q4);  INS(kc, q2,  q3);
            INS(kc, q1,  q2);  INS(kc, q0,  q1);
            q0 = (q0 > kc) ? q0 : kc;
        }
        const uint32_t thr = q14;
        int n = 0;
        #pragma unroll
        for (int c = 0; c < 128; ++c) {
            const uint32_t kc = pv[(size_t)c * NP];
            if (kc >= thr && n < KSEL) { ids[threadIdx.x][n] = px[(size_t)c * NP]; n++; }
        }
    }
    __syncthreads();

    int cnt = 0;
    if (i < NROW && m == 0) {
        #pragma unroll
        for (int a = 0; a < KSEL; ++a) {
            const uint16_t x = ids[threadIdx.x][a];
            #pragma unroll
            for (int b = 0; b < KSEL; ++b)
                cnt += (x == ids[threadIdx.x + 1][b]) ? 1 : 0;
        }
    }
    #pragma unroll
    for (int off = 32; off; off >>= 1) cnt += __shfl_down(cnt, off);
    if (lane == 0) wsum[wave] = cnt;
    __syncthreads();
    if (threadIdx.x == 0)
        atomicAdd(counter, (unsigned)(wsum[0] + wsum[1] + wsum[2] + wsum[3]));
}

__global__ void knn_finalize(const unsigned* __restrict__ counter, float* __restrict__ out)
{
    out[0] = 1.0f - (float)(*counter) / (float)(NROW * KSEL);
}

// ---------------------------------------------------------------- launch
#define XPAD (4 * 2048)   // staging overrun pad (elements; >= 1 tile needed)
#define SQPAD 512         // sq staging overrun pad (floats)

extern "C" void kernel_launch(void* const* d_in, const int* in_sizes, int n_in,
                              void* d_out, int out_size, void* d_ws, size_t ws_size,
                              hipStream_t stream)
{
    (void)in_sizes; (void)n_in; (void)out_size; (void)ws_size;
    const float* x0 = (const float*)d_in[0];
    const float* x1 = (const float*)d_in[1];
    float* out = (float*)d_out;

    char* ws = (char*)d_ws;
    size_t off = 0;
    bf16_t* xp  = (bf16_t*)(ws + off); off += ((size_t)2 * NP * DIM + XPAD) * sizeof(bf16_t);
    float*  sqh = (float*)(ws + off);  off += ((size_t)2 * NP + SQPAD) * sizeof(float);
    off = (off + 255) & ~(size_t)255;
    uint32_t* pk2 = (uint32_t*)(ws + off); off += (size_t)2 * JC * 4 * NP * sizeof(uint32_t); // 10.5 MB
    uint16_t* px2 = (uint16_t*)(ws + off); off += (size_t)2 * JC * 4 * NP * sizeof(uint16_t); // 5.2 MB
    off = (off + 255) & ~(size_t)255;
    unsigned* counter = (unsigned*)(ws + off);

    knn_convert<<<(2 * NP) / 4, 256, 0, stream>>>(x0, x1, xp, sqh, counter);
    knn_topk<<<dim3(NP / 256, JC, 2), 256, 0, stream>>>(xp, sqh, pk2, px2);
    knn_select_count<<<(2 * NROW + 255) / 256, 256, 0, stream>>>(pk2, px2, counter);
    knn_finalize<<<1, 1, 0, stream>>>(counter, out);
}

// Round 19
// 72.022 us; speedup vs baseline: 1.5893x; 1.5893x over previous
//
#include <hip/hip_runtime.h>
#include <hip/hip_bf16.h>
#include <stdint.h>

#define NROW 10000
#define DIM 128
#define NP 10240          // rows padded to 640 tiles of 16
#define KSEL 15
#define JC 32             // j-chunks; cells per row = JC*4 = 128
#define NTILES (NP / 16)  // 640
#define TPC (NTILES / JC) // 20

typedef __attribute__((ext_vector_type(4))) float f32x4;
typedef __attribute__((ext_vector_type(8))) short s16x8;
using bf16_t = __hip_bfloat16;

#define GLD16(gsrc, ldst)                                                          \
    __builtin_amdgcn_global_load_lds(                                              \
        (const __attribute__((address_space(1))) void*)(gsrc),                     \
        (__attribute__((address_space(3))) void*)(ldst), 16, 0, 0)

// ---------------------------------------------------------------- convert
// One wave per row. Writes X in MFMA-fragment-packed layout; sqh = 1024-0.5*|x|^2
// (MFMA C-in). Pad rows: zero data, sqh=1.0 -> key ~1.0, never beats real (~900+).
__global__ __launch_bounds__(256)
void knn_convert(const float* __restrict__ x0, const float* __restrict__ x1,
                 bf16_t* __restrict__ xp, float* __restrict__ sqh,
                 unsigned* __restrict__ counter)
{
    if (blockIdx.x == 0 && threadIdx.x == 0) *counter = 0u;
    const int rg   = blockIdx.x * 4 + (threadIdx.x >> 6);
    const int lane = threadIdx.x & 63;
    if (rg >= 2 * NP) return;
    const int m = rg >= NP ? 1 : 0;
    const int r = rg - m * NP;
    const float* src = m ? x1 : x0;

    float2 v = make_float2(0.f, 0.f);
    float  s = 0.f;
    if (r < NROW) {
        v = *(const float2*)(src + (size_t)r * DIM + lane * 2);
        s = v.x * v.x + v.y * v.y;
    }
    const uint32_t pk = (uint32_t)__bfloat16_as_ushort(__float2bfloat16(v.x))
                      | ((uint32_t)__bfloat16_as_ushort(__float2bfloat16(v.y)) << 16);
    const int e   = lane * 2;
    const int kk  = e >> 5;
    const int gg  = (e >> 3) & 3;
    const int pos = e & 7;
    const size_t off = ((((size_t)m * NTILES + (r >> 4)) * 4 + kk) * 64
                        + (size_t)(gg * 16 + (r & 15))) * 8 + pos;   // even
    *(uint32_t*)(xp + off) = pk;
    #pragma unroll
    for (int o = 32; o; o >>= 1) s += __shfl_down(s, o);
    if (lane == 0) sqh[m * NP + r] = (r < NROW) ? fmaf(s, -0.5f, 1024.0f) : 1.0f;
}

// ---------------------------------------------------------------- main
// LDS-staged A-stream (round-18 win: topk ~62 -> ~26us). Key = dot + 1024 -
// 0.5*sq[j] (MFMA C-in), 22-bit key + 10-bit chunk-local index. LCAP=1 cell
// max per (i, chunk, group) — 128 cells/row. QUAD B-TILES, double-buffered
// LDS staging via global_load_lds, one barrier/tile.
#define PACKMAX(acc, idxb, Q)                                                     \
    do {                                                                          \
        const uint32_t k0_ = (__float_as_uint((acc)[0]) & 0xFFFFFC00u) | (idxb);  \
        const uint32_t k1_ = (__float_as_uint((acc)[1]) & 0xFFFFFC00u) | ((idxb) | 1u); \
        const uint32_t k2_ = (__float_as_uint((acc)[2]) & 0xFFFFFC00u) | ((idxb) | 2u); \
        const uint32_t k3_ = (__float_as_uint((acc)[3]) & 0xFFFFFC00u) | ((idxb) | 3u); \
        asm("v_max3_u32 %0, %1, %2, %0" : "+v"(Q) : "v"(k0_), "v"(k1_));          \
        asm("v_max3_u32 %0, %1, %2, %0" : "+v"(Q) : "v"(k2_), "v"(k3_));          \
    } while (0)

#define MFMA4(d, set, cin)                                                        \
    f32x4 d = __builtin_amdgcn_mfma_f32_16x16x32_bf16(a0, bfr##set[0], cin, 0, 0, 0); \
    d = __builtin_amdgcn_mfma_f32_16x16x32_bf16(a1, bfr##set[1], d, 0, 0, 0);     \
    d = __builtin_amdgcn_mfma_f32_16x16x32_bf16(a2, bfr##set[2], d, 0, 0, 0);     \
    d = __builtin_amdgcn_mfma_f32_16x16x32_bf16(a3, bfr##set[3], d, 0, 0, 0)

__global__ __launch_bounds__(256, 3)
void knn_topk(const bf16_t* __restrict__ xp, const float* __restrict__ sqh,
              uint32_t* __restrict__ pk2, uint16_t* __restrict__ px2)
{
    __shared__ bf16_t Abuf[2][2048];   // 2 x 4KB j-tile double buffer
    __shared__ float  Sbuf[512];       // chunk sq (TPC*16=320 used; padded)

    const int m     = blockIdx.z;
    const int chunk = blockIdx.y;
    const int ib    = blockIdx.x * 256;
    const int wave  = threadIdx.x >> 6;
    const int lane  = threadIdx.x & 63;
    const int li    = lane & 15;
    const int g     = lane >> 4;
    const int tid   = threadIdx.x;

    const bf16_t* XP = xp + (size_t)m * NP * DIM;
    const float*  SQ = sqh + m * NP;

    const int t0 = chunk * TPC;
    const bf16_t* XC = XP + (size_t)t0 * 2048;
    const float*  SC = SQ + t0 * 16;

    // Stage sq chunk (waves 0,1: 2KB) and A-tile 0; barrier at loop top drains.
    if (wave < 2)
        GLD16(SC + (size_t)(wave * 64 + lane) * 4, &Sbuf[wave * 256]);
    GLD16(XC + (size_t)tid * 8, &Abuf[0][wave * 512]);

    // B fragments for four i-sets (persistent; loaded via normal global loads).
    const int ti0 = (ib >> 4) + wave * 4;
    s16x8 bfr0[4], bfr1[4], bfr2[4], bfr3[4];
    #pragma unroll
    for (int kk = 0; kk < 4; ++kk) {
        const size_t bo = ((size_t)kk * 64 + (size_t)(g * 16 + li)) * 8;
        bfr0[kk] = *(const s16x8*)(XP + (size_t)ti0 * 2048 + bo);
        bfr1[kk] = *(const s16x8*)(XP + (size_t)(ti0 + 1) * 2048 + bo);
        bfr2[kk] = *(const s16x8*)(XP + (size_t)(ti0 + 2) * 2048 + bo);
        bfr3[kk] = *(const s16x8*)(XP + (size_t)(ti0 + 3) * 2048 + bo);
    }

    uint32_t q0 = 0, q1 = 0, q2 = 0, q3 = 0;   // cell max per i-set

    const bf16_t* pf = XC + 2048 + (size_t)tid * 8;   // staging src for tile t+1

    for (int t = 0; t < TPC; ++t) {
        __syncthreads();   // buf[t&1] staged (iter t-1) & prior reads of buf[(t+1)&1] done

        const bf16_t* ab = &Abuf[t & 1][lane * 8];
        const s16x8 a0 = *(const s16x8*)(ab);
        const s16x8 a1 = *(const s16x8*)(ab + 512);
        const s16x8 a2 = *(const s16x8*)(ab + 1024);
        const s16x8 a3 = *(const s16x8*)(ab + 1536);
        const f32x4 sv = *(const f32x4*)&Sbuf[t * 16 + g * 4];

        // Stage tile t+1 (lands during this tile's MFMAs; overrun reads pad).
        GLD16(pf, &Abuf[(t + 1) & 1][wave * 512]);
        pf += 2048;

        MFMA4(acc0, 0, sv);
        MFMA4(acc1, 1, sv);
        MFMA4(acc2, 2, sv);
        MFMA4(acc3, 3, sv);

        const uint32_t ib4 = (uint32_t)(t << 2);
        PACKMAX(acc0, ib4, q0);
        PACKMAX(acc1, ib4, q1);
        PACKMAX(acc2, ib4, q2);
        PACKMAX(acc3, ib4, q3);
    }

    // Store cell max + reconstructed j. Plane = (m*JC+chunk)*4 + g, index i.
    const size_t base = ((size_t)((m * JC + chunk) * 4 + g)) * NP;
    #pragma unroll
    for (int s = 0; s < 4; ++s) {
        const uint32_t q = (s == 0) ? q0 : (s == 1) ? q1 : (s == 2) ? q2 : q3;
        const uint32_t id = q & 1023u;
        const int j = (t0 + (int)(id >> 2)) * 16 + g * 4 + (int)(id & 3u);
        const int i = ib + wave * 64 + s * 16 + li;
        pk2[base + i] = q;
        px2[base + i] = (uint16_t)j;
    }
}

// ---------------------------------------------------------------- select stage 1
// One thread per (row, m, half): 64 cell maxes into REGISTER ARRAYS (all loads
// independent & in flight — the round-16-proven pattern; 128 would spill,
// streaming would serialize). med3-chain top-15, threshold-rescan, write the
// 15 survivors (unsorted) compactly.
#define INS(k, hi, lo) asm("v_med3_u32 %0, %1, %2, %0" : "+v"(lo) : "v"(k), "v"(hi))

__global__ __launch_bounds__(256, 1)
void knn_select_half(const uint32_t* __restrict__ pk2, const uint16_t* __restrict__ px2,
                     uint32_t* __restrict__ sk, uint16_t* __restrict__ sx)
{
    const int i = blockIdx.x * 256 + threadIdx.x;   // row
    const int m = blockIdx.y;
    const int h = blockIdx.z;
    if (i >= NROW) return;

    const uint32_t* pv = pk2 + ((size_t)(m * 128 + h * 64)) * NP + i;
    const uint16_t* px = px2 + ((size_t)(m * 128 + h * 64)) * NP + i;

    uint32_t k[64]; uint16_t jx[64];
    #pragma unroll
    for (int c = 0; c < 64; ++c) {
        k[c]  = pv[(size_t)c * NP];
        jx[c] = px[(size_t)c * NP];
    }
    uint32_t q0 = 0, q1 = 0, q2 = 0, q3 = 0, q4 = 0, q5 = 0, q6 = 0, q7 = 0,
             q8 = 0, q9 = 0, q10 = 0, q11 = 0, q12 = 0, q13 = 0, q14 = 0;
    #pragma unroll
    for (int c = 0; c < 64; ++c) {
        const uint32_t kc = k[c];
        INS(kc, q13, q14); INS(kc, q12, q13); INS(kc, q11, q12); INS(kc, q10, q11);
        INS(kc, q9,  q10); INS(kc, q8,  q9);  INS(kc, q7,  q8);  INS(kc, q6,  q7);
        INS(kc, q5,  q6);  INS(kc, q4,  q5);  INS(kc, q3,  q4);  INS(kc, q2,  q3);
        INS(kc, q1,  q2);  INS(kc, q0,  q1);
        q0 = (q0 > kc) ? q0 : kc;
    }
    const uint32_t thr = q14;
    uint32_t* ok = sk + ((size_t)(m * 2 + h) * KSEL) * NROW + i;
    uint16_t* ox = sx + ((size_t)(m * 2 + h) * KSEL) * NROW + i;
    int n = 0;
    #pragma unroll
    for (int c = 0; c < 64; ++c) {
        if (k[c] >= thr && n < KSEL) {
            ok[(size_t)n * NROW] = k[c];
            ox[(size_t)n * NROW] = jx[c];
            n++;
        }
    }
}

// ---------------------------------------------------------------- select stage 2
// Per (row, m): 30 independent coalesced loads (15+15 keys/ids, STATIC indexing),
// med3-chain over 30 -> thr, rescan -> 15 ids into LDS; even threads count the
// 15x15 intersection with their odd partner.
__global__ __launch_bounds__(256, 1)
void knn_merge_count(const uint32_t* __restrict__ sk, const uint16_t* __restrict__ sx,
                     unsigned* __restrict__ counter)
{
    __shared__ uint16_t ids[256][KSEL + 3];   // 36B row stride -> bank-shifted
    __shared__ int wsum[4];
    const int tid  = blockIdx.x * 256 + threadIdx.x;
    const int m    = tid & 1;
    const int i    = tid >> 1;
    const int lane = threadIdx.x & 63;
    const int wave = threadIdx.x >> 6;

    if (i < NROW) {
        const uint32_t* pv = sk + (size_t)(m * 2 * KSEL) * NROW + i;
        const uint16_t* px = sx + (size_t)(m * 2 * KSEL) * NROW + i;
        uint32_t k[2 * KSEL]; uint16_t jx[2 * KSEL];
        #pragma unroll
        for (int c = 0; c < 2 * KSEL; ++c) {
            k[c]  = pv[(size_t)c * NROW];
            jx[c] = px[(size_t)c * NROW];
        }
        uint32_t q0 = 0, q1 = 0, q2 = 0, q3 = 0, q4 = 0, q5 = 0, q6 = 0, q7 = 0,
                 q8 = 0, q9 = 0, q10 = 0, q11 = 0, q12 = 0, q13 = 0, q14 = 0;
        #pragma unroll
        for (int c = 0; c < 2 * KSEL; ++c) {
            const uint32_t kc = k[c];
            INS(kc, q13, q14); INS(kc, q12, q13); INS(kc, q11, q12); INS(kc, q10, q11);
            INS(kc, q9,  q10); INS(kc, q8,  q9);  INS(kc, q7,  q8);  INS(kc, q6,  q7);
            INS(kc, q5,  q6);  INS(kc, q4,  q5);  INS(kc, q3,  q4);  INS(kc, q2,  q3);
            INS(kc, q1,  q2);  INS(kc, q0,  q1);
            q0 = (q0 > kc) ? q0 : kc;
        }
        const uint32_t thr = q14;
        int n = 0;
        #pragma unroll
        for (int c = 0; c < 2 * KSEL; ++c) {
            if (k[c] >= thr && n < KSEL) { ids[threadIdx.x][n] = jx[c]; n++; }
        }
    }
    __syncthreads();

    int cnt = 0;
    if (i < NROW && m == 0) {
        #pragma unroll
        for (int a = 0; a < KSEL; ++a) {
            const uint16_t x = ids[threadIdx.x][a];
            #pragma unroll
            for (int b = 0; b < KSEL; ++b)
                cnt += (x == ids[threadIdx.x + 1][b]) ? 1 : 0;
        }
    }
    #pragma unroll
    for (int off = 32; off; off >>= 1) cnt += __shfl_down(cnt, off);
    if (lane == 0) wsum[wave] = cnt;
    __syncthreads();
    if (threadIdx.x == 0)
        atomicAdd(counter, (unsigned)(wsum[0] + wsum[1] + wsum[2] + wsum[3]));
}

__global__ void knn_finalize(const unsigned* __restrict__ counter, float* __restrict__ out)
{
    out[0] = 1.0f - (float)(*counter) / (float)(NROW * KSEL);
}

// ---------------------------------------------------------------- launch
#define XPAD (4 * 2048)   // staging overrun pad (elements; >= 1 tile needed)
#define SQPAD 512         // sq staging overrun pad (floats)

extern "C" void kernel_launch(void* const* d_in, const int* in_sizes, int n_in,
                              void* d_out, int out_size, void* d_ws, size_t ws_size,
                              hipStream_t stream)
{
    (void)in_sizes; (void)n_in; (void)out_size; (void)ws_size;
    const float* x0 = (const float*)d_in[0];
    const float* x1 = (const float*)d_in[1];
    float* out = (float*)d_out;

    char* ws = (char*)d_ws;
    size_t off = 0;
    bf16_t* xp  = (bf16_t*)(ws + off); off += ((size_t)2 * NP * DIM + XPAD) * sizeof(bf16_t);
    float*  sqh = (float*)(ws + off);  off += ((size_t)2 * NP + SQPAD) * sizeof(float);
    off = (off + 255) & ~(size_t)255;
    uint32_t* pk2 = (uint32_t*)(ws + off); off += (size_t)2 * JC * 4 * NP * sizeof(uint32_t); // 10.5 MB
    uint16_t* px2 = (uint16_t*)(ws + off); off += (size_t)2 * JC * 4 * NP * sizeof(uint16_t); // 5.2 MB
    off = (off + 255) & ~(size_t)255;
    uint32_t* sk = (uint32_t*)(ws + off); off += (size_t)4 * KSEL * NROW * sizeof(uint32_t);  // 2.4 MB
    uint16_t* sx = (uint16_t*)(ws + off); off += (size_t)4 * KSEL * NROW * sizeof(uint16_t);  // 1.2 MB
    off = (off + 255) & ~(size_t)255;
    unsigned* counter = (unsigned*)(ws + off);

    knn_convert<<<(2 * NP) / 4, 256, 0, stream>>>(x0, x1, xp, sqh, counter);
    knn_topk<<<dim3(NP / 256, JC, 2), 256, 0, stream>>>(xp, sqh, pk2, px2);
    knn_select_half<<<dim3((NROW + 255) / 256, 2, 2), 256, 0, stream>>>(pk2, px2, sk, sx);
    knn_merge_count<<<(2 * NROW + 255) / 256, 256, 0, stream>>>(sk, sx, counter);
    knn_finalize<<<1, 1, 0, stream>>>(counter, out);
}

// Round 20
// 71.935 us; speedup vs baseline: 1.5912x; 1.0012x over previous
//
#include <hip/hip_runtime.h>
#include <hip/hip_bf16.h>
#include <stdint.h>

#define NROW 10000
#define DIM 128
#define NP 10240          // rows padded to 640 tiles of 16
#define KSEL 15
#define JC 32             // j-chunks; cells per row = JC*4 = 128
#define NTILES (NP / 16)  // 640
#define TPC (NTILES / JC) // 20

typedef __attribute__((ext_vector_type(4))) float f32x4;
typedef __attribute__((ext_vector_type(8))) short s16x8;
using bf16_t = __hip_bfloat16;

#define GLD16(gsrc, ldst)                                                          \
    __builtin_amdgcn_global_load_lds(                                              \
        (const __attribute__((address_space(1))) void*)(gsrc),                     \
        (__attribute__((address_space(3))) void*)(ldst), 16, 0, 0)

// ---------------------------------------------------------------- convert
// One wave per row. Writes X in MFMA-fragment-packed layout; sqh = 1024-0.5*|x|^2
// (MFMA C-in). Pad rows: zero data, sqh=1.0 -> key ~1.0, never beats real (~900+).
__global__ __launch_bounds__(256)
void knn_convert(const float* __restrict__ x0, const float* __restrict__ x1,
                 bf16_t* __restrict__ xp, float* __restrict__ sqh,
                 unsigned* __restrict__ counter)
{
    if (blockIdx.x == 0 && threadIdx.x == 0) *counter = 0u;
    const int rg   = blockIdx.x * 4 + (threadIdx.x >> 6);
    const int lane = threadIdx.x & 63;
    if (rg >= 2 * NP) return;
    const int m = rg >= NP ? 1 : 0;
    const int r = rg - m * NP;
    const float* src = m ? x1 : x0;

    float2 v = make_float2(0.f, 0.f);
    float  s = 0.f;
    if (r < NROW) {
        v = *(const float2*)(src + (size_t)r * DIM + lane * 2);
        s = v.x * v.x + v.y * v.y;
    }
    const uint32_t pk = (uint32_t)__bfloat16_as_ushort(__float2bfloat16(v.x))
                      | ((uint32_t)__bfloat16_as_ushort(__float2bfloat16(v.y)) << 16);
    const int e   = lane * 2;
    const int kk  = e >> 5;
    const int gg  = (e >> 3) & 3;
    const int pos = e & 7;
    const size_t off = ((((size_t)m * NTILES + (r >> 4)) * 4 + kk) * 64
                        + (size_t)(gg * 16 + (r & 15))) * 8 + pos;   // even
    *(uint32_t*)(xp + off) = pk;
    #pragma unroll
    for (int o = 32; o; o >>= 1) s += __shfl_down(s, o);
    if (lane == 0) sqh[m * NP + r] = (r < NROW) ? fmaf(s, -0.5f, 1024.0f) : 1.0f;
}

// ---------------------------------------------------------------- main
// LDS-staged A-stream, TWO TILES PER BARRIER INTERVAL (round-20 change): each
// iter computes tiles {2p,2p+1} (~450 cyc) while staging {2p+2,2p+3} — compute
// now exceeds staging latency so the pre-barrier vmcnt(0) drain is covered,
// and the two independent tiles let pack-VALU overlap MFMA issue. Half the
// barriers of the 1-tile version. Key = dot + 1024 - 0.5*sq[j] (MFMA C-in),
// 22-bit key + 10-bit chunk-local index. LCAP=1 cell max per (i,chunk,group).
#define PACKMAX(acc, idxb, Q)                                                     \
    do {                                                                          \
        const uint32_t k0_ = (__float_as_uint((acc)[0]) & 0xFFFFFC00u) | (idxb);  \
        const uint32_t k1_ = (__float_as_uint((acc)[1]) & 0xFFFFFC00u) | ((idxb) | 1u); \
        const uint32_t k2_ = (__float_as_uint((acc)[2]) & 0xFFFFFC00u) | ((idxb) | 2u); \
        const uint32_t k3_ = (__float_as_uint((acc)[3]) & 0xFFFFFC00u) | ((idxb) | 3u); \
        asm("v_max3_u32 %0, %1, %2, %0" : "+v"(Q) : "v"(k0_), "v"(k1_));          \
        asm("v_max3_u32 %0, %1, %2, %0" : "+v"(Q) : "v"(k2_), "v"(k3_));          \
    } while (0)

#define MFMA4(d, pre, set, cin)                                                   \
    f32x4 d = __builtin_amdgcn_mfma_f32_16x16x32_bf16(pre##0, bfr##set[0], cin, 0, 0, 0); \
    d = __builtin_amdgcn_mfma_f32_16x16x32_bf16(pre##1, bfr##set[1], d, 0, 0, 0); \
    d = __builtin_amdgcn_mfma_f32_16x16x32_bf16(pre##2, bfr##set[2], d, 0, 0, 0); \
    d = __builtin_amdgcn_mfma_f32_16x16x32_bf16(pre##3, bfr##set[3], d, 0, 0, 0)

__global__ __launch_bounds__(256, 3)
void knn_topk(const bf16_t* __restrict__ xp, const float* __restrict__ sqh,
              uint32_t* __restrict__ pk2, uint16_t* __restrict__ px2)
{
    __shared__ bf16_t Abuf[2][4096];   // 2 buffers x 2 tiles (8KB each)
    __shared__ float  Sbuf[512];       // chunk sq (TPC*16=320 used; padded)

    const int m     = blockIdx.z;
    const int chunk = blockIdx.y;
    const int ib    = blockIdx.x * 256;
    const int wave  = threadIdx.x >> 6;
    const int lane  = threadIdx.x & 63;
    const int li    = lane & 15;
    const int g     = lane >> 4;
    const int tid   = threadIdx.x;

    const bf16_t* XP = xp + (size_t)m * NP * DIM;
    const float*  SQ = sqh + m * NP;

    const int t0 = chunk * TPC;
    const bf16_t* XC = XP + (size_t)t0 * 2048;
    const float*  SC = SQ + t0 * 16;

    // Stage sq chunk (waves 0,1: 2KB) and tiles 0,1 into buf0.
    if (wave < 2)
        GLD16(SC + (size_t)(wave * 64 + lane) * 4, &Sbuf[wave * 256]);
    GLD16(XC + (size_t)tid * 8, &Abuf[0][wave * 512]);
    GLD16(XC + 2048 + (size_t)tid * 8, &Abuf[0][2048 + wave * 512]);

    // B fragments for four i-sets (persistent; loaded via normal global loads).
    const int ti0 = (ib >> 4) + wave * 4;
    s16x8 bfr0[4], bfr1[4], bfr2[4], bfr3[4];
    #pragma unroll
    for (int kk = 0; kk < 4; ++kk) {
        const size_t bo = ((size_t)kk * 64 + (size_t)(g * 16 + li)) * 8;
        bfr0[kk] = *(const s16x8*)(XP + (size_t)ti0 * 2048 + bo);
        bfr1[kk] = *(const s16x8*)(XP + (size_t)(ti0 + 1) * 2048 + bo);
        bfr2[kk] = *(const s16x8*)(XP + (size_t)(ti0 + 2) * 2048 + bo);
        bfr3[kk] = *(const s16x8*)(XP + (size_t)(ti0 + 3) * 2048 + bo);
    }

    uint32_t q0 = 0, q1 = 0, q2 = 0, q3 = 0;   // cell max per i-set

    const bf16_t* pf = XC + 2 * 2048 + (size_t)tid * 8;   // staging src (tiles 2p+2,2p+3)

    for (int p = 0; p < TPC / 2; ++p) {
        __syncthreads();   // buf[p&1] staged; prior reads of buf[(p+1)&1] done

        const bf16_t* abA = &Abuf[p & 1][lane * 8];
        const s16x8 a0 = *(const s16x8*)(abA);
        const s16x8 a1 = *(const s16x8*)(abA + 512);
        const s16x8 a2 = *(const s16x8*)(abA + 1024);
        const s16x8 a3 = *(const s16x8*)(abA + 1536);
        const s16x8 b0 = *(const s16x8*)(abA + 2048);
        const s16x8 b1 = *(const s16x8*)(abA + 2048 + 512);
        const s16x8 b2 = *(const s16x8*)(abA + 2048 + 1024);
        const s16x8 b3 = *(const s16x8*)(abA + 2048 + 1536);
        const f32x4 svA = *(const f32x4*)&Sbuf[(2 * p) * 16 + g * 4];
        const f32x4 svB = *(const f32x4*)&Sbuf[(2 * p + 1) * 16 + g * 4];

        // Stage tiles 2p+2, 2p+3 (land during this iter's 32 MFMAs; overrun pads).
        GLD16(pf, &Abuf[(p + 1) & 1][wave * 512]);
        GLD16(pf + 2048, &Abuf[(p + 1) & 1][2048 + wave * 512]);
        pf += 4096;

        // Tile 2p (A-frags a*), all four i-sets.
        {
            MFMA4(acc0, a, 0, svA);
            MFMA4(acc1, a, 1, svA);
            MFMA4(acc2, a, 2, svA);
            MFMA4(acc3, a, 3, svA);
            const uint32_t ib4 = (uint32_t)((2 * p) << 2);
            PACKMAX(acc0, ib4, q0);
            PACKMAX(acc1, ib4, q1);
            PACKMAX(acc2, ib4, q2);
            PACKMAX(acc3, ib4, q3);
        }
        // Tile 2p+1 (A-frags b*), all four i-sets.
        {
            MFMA4(acc0, b, 0, svB);
            MFMA4(acc1, b, 1, svB);
            MFMA4(acc2, b, 2, svB);
            MFMA4(acc3, b, 3, svB);
            const uint32_t ib4 = (uint32_t)((2 * p + 1) << 2);
            PACKMAX(acc0, ib4, q0);
            PACKMAX(acc1, ib4, q1);
            PACKMAX(acc2, ib4, q2);
            PACKMAX(acc3, ib4, q3);
        }
    }

    // Store cell max + reconstructed j. Plane = (m*JC+chunk)*4 + g, index i.
    const size_t base = ((size_t)((m * JC + chunk) * 4 + g)) * NP;
    #pragma unroll
    for (int s = 0; s < 4; ++s) {
        const uint32_t q = (s == 0) ? q0 : (s == 1) ? q1 : (s == 2) ? q2 : q3;
        const uint32_t id = q & 1023u;
        const int j = (t0 + (int)(id >> 2)) * 16 + g * 4 + (int)(id & 3u);
        const int i = ib + wave * 64 + s * 16 + li;
        pk2[base + i] = q;
        px2[base + i] = (uint16_t)j;
    }
}

// ---------------------------------------------------------------- select stage 1
// One thread per (row, m, half): 64 cell maxes into REGISTER ARRAYS (all loads
// independent & in flight). med3-chain top-15, threshold-rescan, write the 15
// survivors (unsorted) compactly.
#define INS(k, hi, lo) asm("v_med3_u32 %0, %1, %2, %0" : "+v"(lo) : "v"(k), "v"(hi))

__global__ __launch_bounds__(256, 1)
void knn_select_half(const uint32_t* __restrict__ pk2, const uint16_t* __restrict__ px2,
                     uint32_t* __restrict__ sk, uint16_t* __restrict__ sx)
{
    const int i = blockIdx.x * 256 + threadIdx.x;   // row
    const int m = blockIdx.y;
    const int h = blockIdx.z;
    if (i >= NROW) return;

    const uint32_t* pv = pk2 + ((size_t)(m * 128 + h * 64)) * NP + i;
    const uint16_t* px = px2 + ((size_t)(m * 128 + h * 64)) * NP + i;

    uint32_t k[64]; uint16_t jx[64];
    #pragma unroll
    for (int c = 0; c < 64; ++c) {
        k[c]  = pv[(size_t)c * NP];
        jx[c] = px[(size_t)c * NP];
    }
    uint32_t q0 = 0, q1 = 0, q2 = 0, q3 = 0, q4 = 0, q5 = 0, q6 = 0, q7 = 0,
             q8 = 0, q9 = 0, q10 = 0, q11 = 0, q12 = 0, q13 = 0, q14 = 0;
    #pragma unroll
    for (int c = 0; c < 64; ++c) {
        const uint32_t kc = k[c];
        INS(kc, q13, q14); INS(kc, q12, q13); INS(kc, q11, q12); INS(kc, q10, q11);
        INS(kc, q9,  q10); INS(kc, q8,  q9);  INS(kc, q7,  q8);  INS(kc, q6,  q7);
        INS(kc, q5,  q6);  INS(kc, q4,  q5);  INS(kc, q3,  q4);  INS(kc, q2,  q3);
        INS(kc, q1,  q2);  INS(kc, q0,  q1);
        q0 = (q0 > kc) ? q0 : kc;
    }
    const uint32_t thr = q14;
    uint32_t* ok = sk + ((size_t)(m * 2 + h) * KSEL) * NROW + i;
    uint16_t* ox = sx + ((size_t)(m * 2 + h) * KSEL) * NROW + i;
    int n = 0;
    #pragma unroll
    for (int c = 0; c < 64; ++c) {
        if (k[c] >= thr && n < KSEL) {
            ok[(size_t)n * NROW] = k[c];
            ox[(size_t)n * NROW] = jx[c];
            n++;
        }
    }
}

// ---------------------------------------------------------------- select stage 2
// Per (row, m): 30 independent coalesced loads (static indexing), med3-chain
// over 30 -> thr, rescan -> 15 ids into LDS; even threads count the 15x15
// intersection with their odd partner.
__global__ __launch_bounds__(256, 1)
void knn_merge_count(const uint32_t* __restrict__ sk, const uint16_t* __restrict__ sx,
                     unsigned* __restrict__ counter)
{
    __shared__ uint16_t ids[256][KSEL + 3];   // 36B row stride -> bank-shifted
    __shared__ int wsum[4];
    const int tid  = blockIdx.x * 256 + threadIdx.x;
    const int m    = tid & 1;
    const int i    = tid >> 1;
    const int lane = threadIdx.x & 63;
    const int wave = threadIdx.x >> 6;

    if (i < NROW) {
        const uint32_t* pv = sk + (size_t)(m * 2 * KSEL) * NROW + i;
        const uint16_t* px = sx + (size_t)(m * 2 * KSEL) * NROW + i;
        uint32_t k[2 * KSEL]; uint16_t jx[2 * KSEL];
        #pragma unroll
        for (int c = 0; c < 2 * KSEL; ++c) {
            k[c]  = pv[(size_t)c * NROW];
            jx[c] = px[(size_t)c * NROW];
        }
        uint32_t q0 = 0, q1 = 0, q2 = 0, q3 = 0, q4 = 0, q5 = 0, q6 = 0, q7 = 0,
                 q8 = 0, q9 = 0, q10 = 0, q11 = 0, q12 = 0, q13 = 0, q14 = 0;
        #pragma unroll
        for (int c = 0; c < 2 * KSEL; ++c) {
            const uint32_t kc = k[c];
            INS(kc, q13, q14); INS(kc, q12, q13); INS(kc, q11, q12); INS(kc, q10, q11);
            INS(kc, q9,  q10); INS(kc, q8,  q9);  INS(kc, q7,  q8);  INS(kc, q6,  q7);
            INS(kc, q5,  q6);  INS(kc, q4,  q5);  INS(kc, q3,  q4);  INS(kc, q2,  q3);
            INS(kc, q1,  q2);  INS(kc, q0,  q1);
            q0 = (q0 > kc) ? q0 : kc;
        }
        const uint32_t thr = q14;
        int n = 0;
        #pragma unroll
        for (int c = 0; c < 2 * KSEL; ++c) {
            if (k[c] >= thr && n < KSEL) { ids[threadIdx.x][n] = jx[c]; n++; }
        }
    }
    __syncthreads();

    int cnt = 0;
    if (i < NROW && m == 0) {
        #pragma unroll
        for (int a = 0; a < KSEL; ++a) {
            const uint16_t x = ids[threadIdx.x][a];
            #pragma unroll
            for (int b = 0; b < KSEL; ++b)
                cnt += (x == ids[threadIdx.x + 1][b]) ? 1 : 0;
        }
    }
    #pragma unroll
    for (int off = 32; off; off >>= 1) cnt += __shfl_down(cnt, off);
    if (lane == 0) wsum[wave] = cnt;
    __syncthreads();
    if (threadIdx.x == 0)
        atomicAdd(counter, (unsigned)(wsum[0] + wsum[1] + wsum[2] + wsum[3]));
}

__global__ void knn_finalize(const unsigned* __restrict__ counter, float* __restrict__ out)
{
    out[0] = 1.0f - (float)(*counter) / (float)(NROW * KSEL);
}

// ---------------------------------------------------------------- launch
#define XPAD (4 * 2048)   // staging overrun pad (elements; >= 2 tiles needed)
#define SQPAD 512         // sq staging overrun pad (floats)

extern "C" void kernel_launch(void* const* d_in, const int* in_sizes, int n_in,
                              void* d_out, int out_size, void* d_ws, size_t ws_size,
                              hipStream_t stream)
{
    (void)in_sizes; (void)n_in; (void)out_size; (void)ws_size;
    const float* x0 = (const float*)d_in[0];
    const float* x1 = (const float*)d_in[1];
    float* out = (float*)d_out;

    char* ws = (char*)d_ws;
    size_t off = 0;
    bf16_t* xp  = (bf16_t*)(ws + off); off += ((size_t)2 * NP * DIM + XPAD) * sizeof(bf16_t);
    float*  sqh = (float*)(ws + off);  off += ((size_t)2 * NP + SQPAD) * sizeof(float);
    off = (off + 255) & ~(size_t)255;
    uint32_t* pk2 = (uint32_t*)(ws + off); off += (size_t)2 * JC * 4 * NP * sizeof(uint32_t); // 10.5 MB
    uint16_t* px2 = (uint16_t*)(ws + off); off += (size_t)2 * JC * 4 * NP * sizeof(uint16_t); // 5.2 MB
    off = (off + 255) & ~(size_t)255;
    uint32_t* sk = (uint32_t*)(ws + off); off += (size_t)4 * KSEL * NROW * sizeof(uint32_t);  // 2.4 MB
    uint16_t* sx = (uint16_t*)(ws + off); off += (size_t)4 * KSEL * NROW * sizeof(uint16_t);  // 1.2 MB
    off = (off + 255) & ~(size_t)255;
    unsigned* counter = (unsigned*)(ws + off);

    knn_convert<<<(2 * NP) / 4, 256, 0, stream>>>(x0, x1, xp, sqh, counter);
    knn_topk<<<dim3(NP / 256, JC, 2), 256, 0, stream>>>(xp, sqh, pk2, px2);
    knn_select_half<<<dim3((NROW + 255) / 256, 2, 2), 256, 0, stream>>>(pk2, px2, sk, sx);
    knn_merge_count<<<(2 * NROW + 255) / 256, 256, 0, stream>>>(sk, sx, counter);
    knn_finalize<<<1, 1, 0, stream>>>(counter, out);
}